// Round 9
// baseline (760.456 us; speedup 1.0000x reference)
//
#include <hip/hip_runtime.h>
#include <math.h>

#define N_USERS 50000
#define N_ITEMS 100000
#define N_ENT   200000
#define N_NODES (N_USERS + N_ITEMS)
#define N_REL   32
#define DIM     64

#define NB_KG  391          // KG buckets: dst>>9 (512 keys each)
#define NB_UI  586          // UI buckets: row>>8 (256 keys each)
#define NB_TOT (NB_KG + NB_UI)   // 977
#define CAPD   8192         // max edges per bucket in finalize LDS

__device__ __forceinline__ unsigned short f2bf(float f) {   // RNE f32->bf16
    unsigned u = __float_as_uint(f);
    u += 0x7FFFu + ((u >> 16) & 1u);
    return (unsigned short)(u >> 16);
}
__device__ __forceinline__ float bf2f(unsigned short h) {
    return __uint_as_float((unsigned)h << 16);
}

// ---------------------------------------------------------------------------
// ent_matmul: y16 = bf16(x @ W^T), register-tiled LDS GEMM.
// ---------------------------------------------------------------------------
__global__ __launch_bounds__(128) void ent_matmul(const float* __restrict__ x,
                                                  const float* __restrict__ w,
                                                  unsigned short* __restrict__ y16,
                                                  int n_ent) {
    __shared__ float xt[64][132];
    __shared__ float wt[64][68];
    int tid  = threadIdx.x;
    int base = blockIdx.x * 128;

    #pragma unroll
    for (int q = 0; q < 8; q++) {
        int idx = q * 128 + tid;
        int j = idx >> 4, k4 = idx & 15;
        float4 v = ((const float4*)w)[idx];
        wt[4 * k4 + 0][j] = v.x;
        wt[4 * k4 + 1][j] = v.y;
        wt[4 * k4 + 2][j] = v.z;
        wt[4 * k4 + 3][j] = v.w;
    }
    #pragma unroll
    for (int q = 0; q < 16; q++) {
        int idx = q * 128 + tid;
        int r = idx >> 4, k4 = idx & 15;
        int gr = base + r;
        if (gr < n_ent) {
            float4 v = ((const float4*)x)[(long)gr * 16 + k4];
            xt[4 * k4 + 0][r] = v.x;
            xt[4 * k4 + 1][r] = v.y;
            xt[4 * k4 + 2][r] = v.z;
            xt[4 * k4 + 3][r] = v.w;
        }
    }
    __syncthreads();

    int j0 = (tid & 7) * 8;
    int r0 = (tid >> 3) * 8;
    float acc[8][8];
    #pragma unroll
    for (int i = 0; i < 8; i++)
        #pragma unroll
        for (int j = 0; j < 8; j++) acc[i][j] = 0.f;

    #pragma unroll 4
    for (int k = 0; k < 64; k++) {
        float4 xa = *(const float4*)&xt[k][r0];
        float4 xb = *(const float4*)&xt[k][r0 + 4];
        float4 wa = *(const float4*)&wt[k][j0];
        float4 wb = *(const float4*)&wt[k][j0 + 4];
        float xr[8] = {xa.x, xa.y, xa.z, xa.w, xb.x, xb.y, xb.z, xb.w};
        float wr[8] = {wa.x, wa.y, wa.z, wa.w, wb.x, wb.y, wb.z, wb.w};
        #pragma unroll
        for (int i = 0; i < 8; i++)
            #pragma unroll
            for (int j = 0; j < 8; j++)
                acc[i][j] += xr[i] * wr[j];
    }

    #pragma unroll
    for (int i = 0; i < 8; i++) {
        int gr = base + r0 + i;
        if (gr < n_ent) {
            uint4 o;
            o.x = (unsigned)f2bf(acc[i][0]) | ((unsigned)f2bf(acc[i][1]) << 16);
            o.y = (unsigned)f2bf(acc[i][2]) | ((unsigned)f2bf(acc[i][3]) << 16);
            o.z = (unsigned)f2bf(acc[i][4]) | ((unsigned)f2bf(acc[i][5]) << 16);
            o.w = (unsigned)f2bf(acc[i][6]) | ((unsigned)f2bf(acc[i][7]) << 16);
            *(uint4*)&y16[(long)gr * 64 + j0] = o;
        }
    }
}

// ---------------------------------------------------------------------------
// Pass A: per-block LDS bucket histogram
// ---------------------------------------------------------------------------
__global__ __launch_bounds__(256) void bucket_hist(const int* __restrict__ kg_dst,
                                                   const int* __restrict__ ui_row,
                                                   int* __restrict__ bcnt,
                                                   int e_kg, int e_ui) {
    __shared__ int h[NB_TOT];
    for (int i = threadIdx.x; i < NB_TOT; i += 256) h[i] = 0;
    __syncthreads();
    int n = e_kg + e_ui;
    int t = blockIdx.x * 256 + threadIdx.x;
    int stride = gridDim.x * 256;
    for (int e = t; e < n; e += stride) {
        int bk = (e < e_kg) ? (kg_dst[e] >> 9) : (NB_KG + (ui_row[e - e_kg] >> 8));
        atomicAdd(&h[bk], 1);
    }
    __syncthreads();
    for (int i = threadIdx.x; i < NB_TOT; i += 256)
        if (h[i]) atomicAdd(&bcnt[i], h[i]);
}

// ---------------------------------------------------------------------------
// Pass B: exclusive scan of bucket counts
// ---------------------------------------------------------------------------
__global__ __launch_bounds__(256) void bucket_scan(const int* __restrict__ bcnt,
                                                   int* __restrict__ boff_kg,
                                                   int* __restrict__ boff_ui,
                                                   int* __restrict__ bcur,
                                                   int e_kg, int e_ui) {
    __shared__ int sh[1024];
    int t = threadIdx.x;
    for (int seg = 0; seg < 2; seg++) {
        int NB = seg ? NB_UI : NB_KG;
        const int* src = bcnt + (seg ? NB_KG : 0);
        int idx[4] = { t, t + 256, t + 512, t + 768 };
        int v[4];
        #pragma unroll
        for (int q = 0; q < 4; q++) {
            v[q] = (idx[q] < NB) ? src[idx[q]] : 0;
            sh[idx[q]] = v[q];
        }
        __syncthreads();
        for (int o = 1; o < 1024; o <<= 1) {
            int a[4];
            #pragma unroll
            for (int q = 0; q < 4; q++) a[q] = (idx[q] >= o) ? sh[idx[q] - o] : 0;
            __syncthreads();
            #pragma unroll
            for (int q = 0; q < 4; q++) sh[idx[q]] += a[q];
            __syncthreads();
        }
        int* boff = seg ? boff_ui : boff_kg;
        int  base = seg ? NB_KG : 0;
        #pragma unroll
        for (int q = 0; q < 4; q++) {
            if (idx[q] < NB) {
                int ex = sh[idx[q]] - v[q];
                boff[idx[q]] = ex;
                bcur[base + idx[q]] = ex;
            }
        }
        if (t == 0) boff[NB] = seg ? e_ui : e_kg;
        __syncthreads();
    }
}

// ---------------------------------------------------------------------------
// Pass C: scatter edges into bucket regions.
// KG rec: src(18) | rel<<18 (5) | dst_local<<23 (9)
// UI rec: col(18) | row_local<<18 (8)
// ---------------------------------------------------------------------------
__global__ __launch_bounds__(256) void bucket_scatter(const int* __restrict__ kg_src,
                                                      const int* __restrict__ kg_dst,
                                                      const int* __restrict__ kg_rel,
                                                      const int* __restrict__ ui_row,
                                                      const int* __restrict__ ui_col,
                                                      int* __restrict__ bcur,
                                                      unsigned int* __restrict__ kgrec,
                                                      int* __restrict__ uirec,
                                                      int e_kg, int e_ui) {
    __shared__ int h[NB_TOT];
    __shared__ int lbase[NB_TOT];
    int n = e_kg + e_ui;
    int nchunks = (n + 4095) >> 12;
    int tid = threadIdx.x;
    for (int c = blockIdx.x; c < nchunks; c += gridDim.x) {
        int base = c << 12;
        for (int i = tid; i < NB_TOT; i += 256) h[i] = 0;
        __syncthreads();
        unsigned int rec[16];
        int bk[16];
        #pragma unroll
        for (int j = 0; j < 16; j++) {
            int e = base + j * 256 + tid;
            if (e < n) {
                if (e < e_kg) {
                    int d = kg_dst[e];
                    bk[j]  = d >> 9;
                    rec[j] = (unsigned int)kg_src[e] | ((unsigned int)kg_rel[e] << 18)
                             | ((unsigned int)(d & 511) << 23);
                } else {
                    int i2 = e - e_kg;
                    int r  = ui_row[i2];
                    bk[j]  = NB_KG + (r >> 8);
                    rec[j] = (unsigned int)ui_col[i2] | ((unsigned int)(r & 255) << 18);
                }
                atomicAdd(&h[bk[j]], 1);
            } else bk[j] = -1;
        }
        __syncthreads();
        for (int i = tid; i < NB_TOT; i += 256) {
            int cc = h[i];
            lbase[i] = cc ? atomicAdd(&bcur[i], cc) : 0;
        }
        __syncthreads();
        #pragma unroll
        for (int j = 0; j < 16; j++) {
            if (bk[j] >= 0) {
                int pos = atomicAdd(&lbase[bk[j]], 1);
                if (bk[j] < NB_KG) kgrec[pos] = rec[j];
                else               uirec[pos] = (int)rec[j];
            }
        }
        __syncthreads();
    }
}

// ---------------------------------------------------------------------------
// Pass D: one block per bucket. LDS counting-sort; emits CSR off[], sorted
// records, and (UI) dinv[].
// ---------------------------------------------------------------------------
__global__ __launch_bounds__(256) void bucket_finalize(const int* __restrict__ boff_kg,
                                                       const int* __restrict__ boff_ui,
                                                       unsigned int* __restrict__ kgrec,
                                                       int* __restrict__ uirec,
                                                       int* __restrict__ off_kg,
                                                       int* __restrict__ off_ui,
                                                       float* __restrict__ dinv,
                                                       int e_kg, int e_ui) {
    __shared__ unsigned int rec[CAPD];
    __shared__ int hist[512];
    bool iskg = blockIdx.x < NB_KG;
    int  b    = iskg ? blockIdx.x : blockIdx.x - NB_KG;
    const int* boff = iskg ? boff_kg : boff_ui;
    int ebeg = boff[b], eend = boff[b + 1];
    int ne   = min(eend - ebeg, CAPD);
    int key_base = iskg ? (b << 9) : (b << 8);
    int nkeys = iskg ? min(512, N_ENT - key_base) : min(256, N_NODES - key_base);
    int SH = iskg ? 23 : 18;
    int tid = threadIdx.x;

    for (int i = tid; i < ne; i += 256)
        rec[i] = iskg ? kgrec[ebeg + i] : (unsigned int)uirec[ebeg + i];
    for (int i = tid; i < 512; i += 256) hist[i] = 0;
    __syncthreads();
    for (int i = tid; i < ne; i += 256)
        atomicAdd(&hist[rec[i] >> SH], 1);
    __syncthreads();
    if (!iskg) {
        for (int i = tid; i < nkeys; i += 256) {
            int d = hist[i];
            dinv[key_base + i] = d > 0 ? 1.0f / sqrtf((float)d) : 0.0f;
        }
    }
    int i0 = tid, i1 = tid + 256;
    int v0 = hist[i0], v1 = hist[i1];
    __syncthreads();
    for (int o = 1; o < 512; o <<= 1) {
        int a0 = (i0 >= o) ? hist[i0 - o] : 0;
        int a1 = (i1 >= o) ? hist[i1 - o] : 0;
        __syncthreads();
        hist[i0] += a0; hist[i1] += a1;
        __syncthreads();
    }
    int e0 = hist[i0] - v0, e1 = hist[i1] - v1;
    __syncthreads();
    hist[i0] = e0; hist[i1] = e1;
    int* offg = iskg ? off_kg : off_ui;
    if (i0 < nkeys) offg[key_base + i0] = ebeg + e0;
    if (i1 < nkeys) offg[key_base + i1] = ebeg + e1;
    if (blockIdx.x == 0 && tid == 0) {
        off_kg[N_ENT]   = e_kg;
        off_ui[N_NODES] = e_ui;
    }
    __syncthreads();
    for (int i = tid; i < ne; i += 256) {
        unsigned int r = rec[i];
        int k = r >> SH;
        int slot = atomicAdd(&hist[k], 1);
        if (iskg) kgrec[ebeg + slot] = r & 0x7FFFFFu;
        else      uirec[ebeg + slot] = (int)(r & 0x3FFFFu);
    }
}

// ---------------------------------------------------------------------------
// kg_aggregate: each wave owns a CONTIGUOUS row range -> its edges form one
// contiguous CSR span. Flat edge loop, 8 gathers in flight regardless of
// degree; rows flushed in-register at boundaries (no atomics, fused epilogue).
// ---------------------------------------------------------------------------
__global__ __launch_bounds__(256) void kg_aggregate(const int* __restrict__ off,
                                                    const unsigned int* __restrict__ packed,
                                                    const unsigned short* __restrict__ y16,
                                                    const float* __restrict__ x0,
                                                    const float* __restrict__ rel_emb,
                                                    float* __restrict__ xkg, int n_ent) {
    __shared__ float gate[N_REL * 64];
    for (int idx = threadIdx.x; idx < N_REL * 64; idx += blockDim.x)
        gate[idx] = 1.0f / (1.0f + __expf(-rel_emb[idx]));
    __syncthreads();
    int lane = threadIdx.x & 63;
    int wid  = (blockIdx.x * blockDim.x + threadIdx.x) >> 6;
    int nw   = (gridDim.x * blockDim.x) >> 6;
    int rpw  = (n_ent + nw - 1) / nw;
    int r0   = wid * rpw;
    if (r0 >= n_ent) return;
    int r1 = min(r0 + rpw, n_ent);

    int r    = r0;
    int beg  = off[r];
    int next = off[r + 1];
    int e    = beg;
    int e_end = off[r1];
    float acc = 0.f;

    auto flush = [&](int rr, int cnt) {
        float deg = fmaxf((float)cnt, 1.0f);
        float v = acc / deg + x0[(long)rr * 64 + lane];
        v = (v > 0.0f) ? v : (__expf(v) - 1.0f);      // elu
        float ss = v * v;
        #pragma unroll
        for (int o = 32; o; o >>= 1) ss += __shfl_xor(ss, o);
        xkg[(long)rr * 64 + lane] = v / fmaxf(sqrtf(ss), 1e-12f);
    };

    // leading empty rows
    while (r < r1 && e >= next) {
        flush(r, next - beg);
        acc = 0.f;
        beg = next;
        r++;
        if (r < r1) next = off[r + 1];
    }

    while (e < e_end) {
        int m = min(8, e_end - e);
        float v[8];
        #pragma unroll
        for (int q = 0; q < 8; q++) {
            if (q < m) {
                unsigned int pk = packed[e + q];
                v[q] = bf2f(y16[(long)(pk & 0x3FFFF) * 64 + lane])
                     * gate[(pk >> 18) * 64 + lane];
            }
        }
        #pragma unroll
        for (int q = 0; q < 8; q++) {
            if (q < m) {
                acc += v[q];
                int epos = e + q + 1;
                while (r < r1 && epos >= next) {
                    flush(r, next - beg);
                    acc = 0.f;
                    beg = next;
                    r++;
                    if (r < r1) next = off[r + 1];
                }
            }
        }
        e += m;
    }
}

// ---------------------------------------------------------------------------
// build_all: all_emb = [user_emb ; xkg[i2e]] (f32) + bf16 gather copy all16
// ---------------------------------------------------------------------------
__global__ void build_all(const float* __restrict__ user_emb, const float* __restrict__ xkg,
                          const int* __restrict__ i2e, float* __restrict__ all_emb,
                          unsigned short* __restrict__ all16) {
    int lane = threadIdx.x & 63;
    int wave = (blockIdx.x * blockDim.x + threadIdx.x) >> 6;
    int nw   = (gridDim.x * blockDim.x) >> 6;
    for (int r = wave; r < N_NODES; r += nw) {
        float v;
        if (r < N_USERS) {
            v = user_emb[(long)r * 64 + lane];
        } else {
            long ent = i2e[r - N_USERS];
            v = xkg[ent * 64 + lane];
        }
        all_emb[(long)r * 64 + lane] = v;
        all16[(long)r * 64 + lane]   = f2bf(v);
    }
}

// ---------------------------------------------------------------------------
// ui_aggregate: same contiguous-row flat edge-walk; val = dinv[r]*dinv[c].
// final = 0.5*(all_emb[r] + dinv[r]*sum(dinv[c]*all16[c]))
// ---------------------------------------------------------------------------
__global__ __launch_bounds__(256) void ui_aggregate(const int* __restrict__ off,
                                                    const int* __restrict__ colrec,
                                                    const float* __restrict__ all_emb,
                                                    const unsigned short* __restrict__ all16,
                                                    const float* __restrict__ dinv,
                                                    float* __restrict__ final_emb) {
    int lane = threadIdx.x & 63;
    int wid  = (blockIdx.x * blockDim.x + threadIdx.x) >> 6;
    int nw   = (gridDim.x * blockDim.x) >> 6;
    int rpw  = (N_NODES + nw - 1) / nw;
    int r0   = wid * rpw;
    if (r0 >= N_NODES) return;
    int r1 = min(r0 + rpw, N_NODES);

    int r    = r0;
    int beg  = off[r];
    int next = off[r + 1];
    int e    = beg;
    int e_end = off[r1];
    float acc = 0.f;

    auto flush = [&](int rr) {
        float a = acc * dinv[rr];
        final_emb[(long)rr * 64 + lane] =
            0.5f * (all_emb[(long)rr * 64 + lane] + a);
    };

    while (r < r1 && e >= next) {
        flush(r);
        acc = 0.f;
        beg = next;
        r++;
        if (r < r1) next = off[r + 1];
    }

    while (e < e_end) {
        int m = min(8, e_end - e);
        float v[8];
        #pragma unroll
        for (int q = 0; q < 8; q++) {
            if (q < m) {
                int c = colrec[e + q];
                v[q] = dinv[c] * bf2f(all16[(long)c * 64 + lane]);
            }
        }
        #pragma unroll
        for (int q = 0; q < 8; q++) {
            if (q < m) {
                acc += v[q];
                int epos = e + q + 1;
                while (r < r1 && epos >= next) {
                    flush(r);
                    acc = 0.f;
                    beg = next;
                    r++;
                    if (r < r1) next = off[r + 1];
                }
            }
        }
        e += m;
    }
}

// ---------------------------------------------------------------------------
// Epilogue (intent folded in): one wave per sample.
// ---------------------------------------------------------------------------
__global__ void final_kernel(const int* __restrict__ u, const int* __restrict__ ipos,
                             const int* __restrict__ ineg,
                             const float* __restrict__ final_emb,
                             const float* __restrict__ all_emb,
                             const float* __restrict__ rw, const float* __restrict__ rb,
                             const float* __restrict__ iw, const float* __restrict__ rel_emb,
                             float* __restrict__ out, int B) {
    __shared__ float sh_intent[128];
    if (threadIdx.x < 64) {
        int j = threadIdx.x;
        for (int k = 0; k < 2; k++) {
            float m = -1e30f;
            for (int r = 0; r < N_REL; r++) m = fmaxf(m, iw[k * N_REL + r]);
            float Z = 0.f, acc = 0.f;
            for (int r = 0; r < N_REL; r++) {
                float e = __expf(iw[k * N_REL + r] - m);
                Z += e;
                acc += e * rel_emb[r * 64 + j];
            }
            sh_intent[k * 64 + j] = acc / Z;
        }
    }
    __syncthreads();
    int lane = threadIdx.x & 63;
    int wave = (blockIdx.x * blockDim.x + threadIdx.x) >> 6;
    int nw   = (gridDim.x * blockDim.x) >> 6;
    for (int b = wave; b < B; b += nw) {
        int uu = u[b];
        float up = final_emb[(long)uu * 64 + lane];
        float l0 = up * rw[lane];
        float l1 = up * rw[64 + lane];
        #pragma unroll
        for (int o = 32; o; o >>= 1) {
            l0 += __shfl_xor(l0, o);
            l1 += __shfl_xor(l1, o);
        }
        l0 += rb[0]; l1 += rb[1];
        float m  = fmaxf(l0, l1);
        float e0 = __expf(l0 - m), e1 = __expf(l1 - m);
        float inv = 1.0f / (e0 + e1);
        float p0 = e0 * inv, p1 = e1 * inv;
        float ue = up + p0 * sh_intent[lane] + p1 * sh_intent[64 + lane];

        int it = ipos[b];
        long rr = (long)(N_USERS + it) * 64 + lane;
        float ie = final_emb[rr] + all_emb[rr];
        float dp = ue * ie;
        #pragma unroll
        for (int o = 32; o; o >>= 1) dp += __shfl_xor(dp, o);
        if (lane == 0) out[b] = dp;

        it = ineg[b];
        rr = (long)(N_USERS + it) * 64 + lane;
        ie = final_emb[rr] + all_emb[rr];
        dp = ue * ie;
        #pragma unroll
        for (int o = 32; o; o >>= 1) dp += __shfl_xor(dp, o);
        if (lane == 0) out[B + b] = dp;
    }
}

extern "C" void kernel_launch(void* const* d_in, const int* in_sizes, int n_in,
                              void* d_out, int out_size, void* d_ws, size_t ws_size,
                              hipStream_t stream) {
    const int*   u          = (const int*)  d_in[0];
    const int*   ipos       = (const int*)  d_in[1];
    const int*   ineg       = (const int*)  d_in[2];
    const float* user_emb   = (const float*)d_in[3];
    const float* entity_emb = (const float*)d_in[4];
    const float* rel_emb    = (const float*)d_in[5];
    const float* iw         = (const float*)d_in[6];
    const float* rw         = (const float*)d_in[7];
    const float* rb         = (const float*)d_in[8];
    const float* kgw        = (const float*)d_in[9];
    const int*   i2e        = (const int*)  d_in[11];
    const int*   kg_src     = (const int*)  d_in[12];
    const int*   kg_dst     = (const int*)  d_in[13];
    const int*   kg_rel     = (const int*)  d_in[14];
    const int*   ui_row     = (const int*)  d_in[15];
    const int*   ui_col     = (const int*)  d_in[16];
    float*       out        = (float*)d_out;

    int B    = in_sizes[0];
    int e_kg = in_sizes[12];
    int e_ui = in_sizes[15];

    // ---------------- workspace layout (bytes) ----------------
    char* ws = (char*)d_ws;
    unsigned short* y16       = (unsigned short*)(ws + 0);   // 25.6 MB
    float*          all_emb   = (float*)(ws + 0);            // 38.4 MB (after kg_agg)
    float*          xkg       = (float*)(ws + 38400000);     // 51.2 MB
    float*          final_emb = (float*)(ws + 38400000);     // 38.4 MB (after build_all)
    unsigned short* all16     = (unsigned short*)(ws + 89600000); // 19.2 MB
    unsigned int*   kgrec     = (unsigned int*)(ws + 108800000);  // 8 MB
    int*            uirec     = (int*)(ws + 116800000);      // 8 MB
    int*            off_kg    = (int*)(ws + 124800000);      // 200001 ints
    int*            off_ui    = (int*)(ws + 125600256);      // 150001 ints
    float*          dinv      = (float*)(ws + 126200512);    // 150000 floats
    int*            bcnt      = (int*)(ws + 126800512);      // 977 ints
    int*            boff_kg   = (int*)(ws + 126804480);      // 392 ints
    int*            boff_ui   = (int*)(ws + 126806272);      // 587 ints
    int*            bcur      = (int*)(ws + 126808704);      // 977 ints

    hipMemsetAsync(bcnt, 0, NB_TOT * sizeof(int), stream);
    bucket_hist    <<<256, 256, 0, stream>>>(kg_dst, ui_row, bcnt, e_kg, e_ui);
    bucket_scan    <<<1,   256, 0, stream>>>(bcnt, boff_kg, boff_ui, bcur, e_kg, e_ui);
    bucket_scatter <<<512, 256, 0, stream>>>(kg_src, kg_dst, kg_rel, ui_row, ui_col,
                                             bcur, kgrec, uirec, e_kg, e_ui);
    bucket_finalize<<<NB_TOT, 256, 0, stream>>>(boff_kg, boff_ui, kgrec, uirec,
                                                off_kg, off_ui, dinv, e_kg, e_ui);

    ent_matmul  <<<(N_ENT + 127) / 128, 128, 0, stream>>>(entity_emb, kgw, y16, N_ENT);
    kg_aggregate<<<4096, 256, 0, stream>>>(off_kg, kgrec, y16, entity_emb, rel_emb,
                                           xkg, N_ENT);
    build_all   <<<2048, 256, 0, stream>>>(user_emb, xkg, i2e, all_emb, all16);
    ui_aggregate<<<4096, 256, 0, stream>>>(off_ui, uirec, all_emb, all16, dinv, final_emb);
    final_kernel<<<256,  256, 0, stream>>>(u, ipos, ineg, final_emb, all_emb,
                                           rw, rb, iw, rel_emb, out, B);
}

// Round 10
// 487.405 us; speedup vs baseline: 1.5602x; 1.5602x over previous
//
#include <hip/hip_runtime.h>
#include <math.h>

#define N_USERS 50000
#define N_ITEMS 100000
#define N_ENT   200000
#define N_NODES (N_USERS + N_ITEMS)
#define N_REL   32
#define DIM     64

#define NB_KG  391          // KG buckets: dst>>9 (512 keys each)
#define NB_UI  586          // UI buckets: row>>8 (256 keys each)
#define NB_TOT (NB_KG + NB_UI)   // 977
#define CAPD   8192         // max edges per bucket in finalize LDS

__device__ __forceinline__ unsigned short f2bf(float f) {   // RNE f32->bf16
    unsigned u = __float_as_uint(f);
    u += 0x7FFFu + ((u >> 16) & 1u);
    return (unsigned short)(u >> 16);
}
__device__ __forceinline__ float bf_lo(unsigned v) { return __uint_as_float(v << 16); }
__device__ __forceinline__ float bf_hi(unsigned v) { return __uint_as_float(v & 0xFFFF0000u); }

// ---------------------------------------------------------------------------
// ent_matmul: y16 = bf16(x @ W^T), register-tiled LDS GEMM (R7 form).
// ---------------------------------------------------------------------------
__global__ __launch_bounds__(128) void ent_matmul(const float* __restrict__ x,
                                                  const float* __restrict__ w,
                                                  unsigned short* __restrict__ y16,
                                                  int n_ent) {
    __shared__ float xt[64][132];
    __shared__ float wt[64][68];
    int tid  = threadIdx.x;
    int base = blockIdx.x * 128;

    #pragma unroll
    for (int q = 0; q < 8; q++) {
        int idx = q * 128 + tid;
        int j = idx >> 4, k4 = idx & 15;
        float4 v = ((const float4*)w)[idx];
        wt[4 * k4 + 0][j] = v.x;
        wt[4 * k4 + 1][j] = v.y;
        wt[4 * k4 + 2][j] = v.z;
        wt[4 * k4 + 3][j] = v.w;
    }
    #pragma unroll
    for (int q = 0; q < 16; q++) {
        int idx = q * 128 + tid;
        int r = idx >> 4, k4 = idx & 15;
        int gr = base + r;
        if (gr < n_ent) {
            float4 v = ((const float4*)x)[(long)gr * 16 + k4];
            xt[4 * k4 + 0][r] = v.x;
            xt[4 * k4 + 1][r] = v.y;
            xt[4 * k4 + 2][r] = v.z;
            xt[4 * k4 + 3][r] = v.w;
        }
    }
    __syncthreads();

    int j0 = (tid & 7) * 8;
    int r0 = (tid >> 3) * 8;
    float acc[8][8];
    #pragma unroll
    for (int i = 0; i < 8; i++)
        #pragma unroll
        for (int j = 0; j < 8; j++) acc[i][j] = 0.f;

    #pragma unroll 4
    for (int k = 0; k < 64; k++) {
        float4 xa = *(const float4*)&xt[k][r0];
        float4 xb = *(const float4*)&xt[k][r0 + 4];
        float4 wa = *(const float4*)&wt[k][j0];
        float4 wb = *(const float4*)&wt[k][j0 + 4];
        float xr[8] = {xa.x, xa.y, xa.z, xa.w, xb.x, xb.y, xb.z, xb.w};
        float wr[8] = {wa.x, wa.y, wa.z, wa.w, wb.x, wb.y, wb.z, wb.w};
        #pragma unroll
        for (int i = 0; i < 8; i++)
            #pragma unroll
            for (int j = 0; j < 8; j++)
                acc[i][j] += xr[i] * wr[j];
    }

    #pragma unroll
    for (int i = 0; i < 8; i++) {
        int gr = base + r0 + i;
        if (gr < n_ent) {
            uint4 o;
            o.x = (unsigned)f2bf(acc[i][0]) | ((unsigned)f2bf(acc[i][1]) << 16);
            o.y = (unsigned)f2bf(acc[i][2]) | ((unsigned)f2bf(acc[i][3]) << 16);
            o.z = (unsigned)f2bf(acc[i][4]) | ((unsigned)f2bf(acc[i][5]) << 16);
            o.w = (unsigned)f2bf(acc[i][6]) | ((unsigned)f2bf(acc[i][7]) << 16);
            *(uint4*)&y16[(long)gr * 64 + j0] = o;
        }
    }
}

// ---------------------------------------------------------------------------
// Pass A: per-block LDS bucket histogram
// ---------------------------------------------------------------------------
__global__ __launch_bounds__(256) void bucket_hist(const int* __restrict__ kg_dst,
                                                   const int* __restrict__ ui_row,
                                                   int* __restrict__ bcnt,
                                                   int e_kg, int e_ui) {
    __shared__ int h[NB_TOT];
    for (int i = threadIdx.x; i < NB_TOT; i += 256) h[i] = 0;
    __syncthreads();
    int n = e_kg + e_ui;
    int t = blockIdx.x * 256 + threadIdx.x;
    int stride = gridDim.x * 256;
    for (int e = t; e < n; e += stride) {
        int bk = (e < e_kg) ? (kg_dst[e] >> 9) : (NB_KG + (ui_row[e - e_kg] >> 8));
        atomicAdd(&h[bk], 1);
    }
    __syncthreads();
    for (int i = threadIdx.x; i < NB_TOT; i += 256)
        if (h[i]) atomicAdd(&bcnt[i], h[i]);
}

// ---------------------------------------------------------------------------
// Pass B: exclusive scan of bucket counts
// ---------------------------------------------------------------------------
__global__ __launch_bounds__(256) void bucket_scan(const int* __restrict__ bcnt,
                                                   int* __restrict__ boff_kg,
                                                   int* __restrict__ boff_ui,
                                                   int* __restrict__ bcur,
                                                   int e_kg, int e_ui) {
    __shared__ int sh[1024];
    int t = threadIdx.x;
    for (int seg = 0; seg < 2; seg++) {
        int NB = seg ? NB_UI : NB_KG;
        const int* src = bcnt + (seg ? NB_KG : 0);
        int idx[4] = { t, t + 256, t + 512, t + 768 };
        int v[4];
        #pragma unroll
        for (int q = 0; q < 4; q++) {
            v[q] = (idx[q] < NB) ? src[idx[q]] : 0;
            sh[idx[q]] = v[q];
        }
        __syncthreads();
        for (int o = 1; o < 1024; o <<= 1) {
            int a[4];
            #pragma unroll
            for (int q = 0; q < 4; q++) a[q] = (idx[q] >= o) ? sh[idx[q] - o] : 0;
            __syncthreads();
            #pragma unroll
            for (int q = 0; q < 4; q++) sh[idx[q]] += a[q];
            __syncthreads();
        }
        int* boff = seg ? boff_ui : boff_kg;
        int  base = seg ? NB_KG : 0;
        #pragma unroll
        for (int q = 0; q < 4; q++) {
            if (idx[q] < NB) {
                int ex = sh[idx[q]] - v[q];
                boff[idx[q]] = ex;
                bcur[base + idx[q]] = ex;
            }
        }
        if (t == 0) boff[NB] = seg ? e_ui : e_kg;
        __syncthreads();
    }
}

// ---------------------------------------------------------------------------
// Pass C: scatter edges into bucket regions.
// KG rec: src(18) | rel<<18 (5) | dst_local<<23 (9)
// UI rec: col(18) | row_local<<18 (8)
// ---------------------------------------------------------------------------
__global__ __launch_bounds__(256) void bucket_scatter(const int* __restrict__ kg_src,
                                                      const int* __restrict__ kg_dst,
                                                      const int* __restrict__ kg_rel,
                                                      const int* __restrict__ ui_row,
                                                      const int* __restrict__ ui_col,
                                                      int* __restrict__ bcur,
                                                      unsigned int* __restrict__ kgrec,
                                                      int* __restrict__ uirec,
                                                      int e_kg, int e_ui) {
    __shared__ int h[NB_TOT];
    __shared__ int lbase[NB_TOT];
    int n = e_kg + e_ui;
    int nchunks = (n + 4095) >> 12;
    int tid = threadIdx.x;
    for (int c = blockIdx.x; c < nchunks; c += gridDim.x) {
        int base = c << 12;
        for (int i = tid; i < NB_TOT; i += 256) h[i] = 0;
        __syncthreads();
        unsigned int rec[16];
        int bk[16];
        #pragma unroll
        for (int j = 0; j < 16; j++) {
            int e = base + j * 256 + tid;
            if (e < n) {
                if (e < e_kg) {
                    int d = kg_dst[e];
                    bk[j]  = d >> 9;
                    rec[j] = (unsigned int)kg_src[e] | ((unsigned int)kg_rel[e] << 18)
                             | ((unsigned int)(d & 511) << 23);
                } else {
                    int i2 = e - e_kg;
                    int r  = ui_row[i2];
                    bk[j]  = NB_KG + (r >> 8);
                    rec[j] = (unsigned int)ui_col[i2] | ((unsigned int)(r & 255) << 18);
                }
                atomicAdd(&h[bk[j]], 1);
            } else bk[j] = -1;
        }
        __syncthreads();
        for (int i = tid; i < NB_TOT; i += 256) {
            int cc = h[i];
            lbase[i] = cc ? atomicAdd(&bcur[i], cc) : 0;
        }
        __syncthreads();
        #pragma unroll
        for (int j = 0; j < 16; j++) {
            if (bk[j] >= 0) {
                int pos = atomicAdd(&lbase[bk[j]], 1);
                if (bk[j] < NB_KG) kgrec[pos] = rec[j];
                else               uirec[pos] = (int)rec[j];
            }
        }
        __syncthreads();
    }
}

// ---------------------------------------------------------------------------
// Pass D: one block per bucket. LDS counting-sort; emits CSR off[], sorted
// records, and (UI) dinv[].
// ---------------------------------------------------------------------------
__global__ __launch_bounds__(256) void bucket_finalize(const int* __restrict__ boff_kg,
                                                       const int* __restrict__ boff_ui,
                                                       unsigned int* __restrict__ kgrec,
                                                       int* __restrict__ uirec,
                                                       int* __restrict__ off_kg,
                                                       int* __restrict__ off_ui,
                                                       float* __restrict__ dinv,
                                                       int e_kg, int e_ui) {
    __shared__ unsigned int rec[CAPD];
    __shared__ int hist[512];
    bool iskg = blockIdx.x < NB_KG;
    int  b    = iskg ? blockIdx.x : blockIdx.x - NB_KG;
    const int* boff = iskg ? boff_kg : boff_ui;
    int ebeg = boff[b], eend = boff[b + 1];
    int ne   = min(eend - ebeg, CAPD);
    int key_base = iskg ? (b << 9) : (b << 8);
    int nkeys = iskg ? min(512, N_ENT - key_base) : min(256, N_NODES - key_base);
    int SH = iskg ? 23 : 18;
    int tid = threadIdx.x;

    for (int i = tid; i < ne; i += 256)
        rec[i] = iskg ? kgrec[ebeg + i] : (unsigned int)uirec[ebeg + i];
    for (int i = tid; i < 512; i += 256) hist[i] = 0;
    __syncthreads();
    for (int i = tid; i < ne; i += 256)
        atomicAdd(&hist[rec[i] >> SH], 1);
    __syncthreads();
    if (!iskg) {
        for (int i = tid; i < nkeys; i += 256) {
            int d = hist[i];
            dinv[key_base + i] = d > 0 ? 1.0f / sqrtf((float)d) : 0.0f;
        }
    }
    int i0 = tid, i1 = tid + 256;
    int v0 = hist[i0], v1 = hist[i1];
    __syncthreads();
    for (int o = 1; o < 512; o <<= 1) {
        int a0 = (i0 >= o) ? hist[i0 - o] : 0;
        int a1 = (i1 >= o) ? hist[i1 - o] : 0;
        __syncthreads();
        hist[i0] += a0; hist[i1] += a1;
        __syncthreads();
    }
    int e0 = hist[i0] - v0, e1 = hist[i1] - v1;
    __syncthreads();
    hist[i0] = e0; hist[i1] = e1;
    int* offg = iskg ? off_kg : off_ui;
    if (i0 < nkeys) offg[key_base + i0] = ebeg + e0;
    if (i1 < nkeys) offg[key_base + i1] = ebeg + e1;
    if (blockIdx.x == 0 && tid == 0) {
        off_kg[N_ENT]   = e_kg;
        off_ui[N_NODES] = e_ui;
    }
    __syncthreads();
    for (int i = tid; i < ne; i += 256) {
        unsigned int r = rec[i];
        int k = r >> SH;
        int slot = atomicAdd(&hist[k], 1);
        if (iskg) kgrec[ebeg + slot] = r & 0x7FFFFFu;
        else      uirec[ebeg + slot] = (int)(r & 0x3FFFFu);
    }
}

// ---------------------------------------------------------------------------
// kg_aggregate: row-per-wave (R8 structure) + HALF-WAVE EDGE PAIRING.
// A row's 64 bf16 = 128 B = 32 lanes x 4 B: lanes 0-31 gather edge p's row,
// lanes 32-63 edge p+1's. One gather instruction covers 2 edges; 4-deep
// unroll = 8 edges in flight. Lane (hl) holds dims {2hl, 2hl+1}.
// ---------------------------------------------------------------------------
__global__ __launch_bounds__(256) void kg_aggregate(const int* __restrict__ off,
                                                    const unsigned int* __restrict__ packed,
                                                    const unsigned short* __restrict__ y16,
                                                    const float* __restrict__ x0,
                                                    const float* __restrict__ rel_emb,
                                                    float* __restrict__ xkg, int n_ent) {
    __shared__ float2 gate2[N_REL * 32];   // gate2[rel*32+hl] = sigmoid pair
    for (int idx = threadIdx.x; idx < N_REL * 32; idx += blockDim.x) {
        int rel = idx >> 5, hl = idx & 31;
        float g0 = 1.0f / (1.0f + __expf(-rel_emb[rel * 64 + 2 * hl]));
        float g1 = 1.0f / (1.0f + __expf(-rel_emb[rel * 64 + 2 * hl + 1]));
        gate2[idx] = make_float2(g0, g1);
    }
    __syncthreads();
    const unsigned* y32 = (const unsigned*)y16;
    int lane = threadIdx.x & 63;
    int hl   = lane & 31;
    int half = lane >> 5;
    int wave = (blockIdx.x * blockDim.x + threadIdx.x) >> 6;
    int nw   = (gridDim.x * blockDim.x) >> 6;
    for (int r = wave; r < n_ent; r += nw) {
        int beg = off[r], end = off[r + 1];
        float ax0 = 0.f, ay0 = 0.f, ax1 = 0.f, ay1 = 0.f;
        float ax2 = 0.f, ay2 = 0.f, ax3 = 0.f, ay3 = 0.f;
        int p = beg;
        for (; p + 8 <= end; p += 8) {
            unsigned pk0 = packed[p + 0 + half];
            unsigned pk1 = packed[p + 2 + half];
            unsigned pk2 = packed[p + 4 + half];
            unsigned pk3 = packed[p + 6 + half];
            unsigned v0 = y32[(long)(pk0 & 0x3FFFF) * 32 + hl];
            unsigned v1 = y32[(long)(pk1 & 0x3FFFF) * 32 + hl];
            unsigned v2 = y32[(long)(pk2 & 0x3FFFF) * 32 + hl];
            unsigned v3 = y32[(long)(pk3 & 0x3FFFF) * 32 + hl];
            float2 g0 = gate2[(pk0 >> 18) * 32 + hl];
            float2 g1 = gate2[(pk1 >> 18) * 32 + hl];
            float2 g2 = gate2[(pk2 >> 18) * 32 + hl];
            float2 g3 = gate2[(pk3 >> 18) * 32 + hl];
            ax0 += bf_lo(v0) * g0.x;  ay0 += bf_hi(v0) * g0.y;
            ax1 += bf_lo(v1) * g1.x;  ay1 += bf_hi(v1) * g1.y;
            ax2 += bf_lo(v2) * g2.x;  ay2 += bf_hi(v2) * g2.y;
            ax3 += bf_lo(v3) * g3.x;  ay3 += bf_hi(v3) * g3.y;
        }
        for (; p + 2 <= end; p += 2) {
            unsigned pk = packed[p + half];
            unsigned v  = y32[(long)(pk & 0x3FFFF) * 32 + hl];
            float2 g = gate2[(pk >> 18) * 32 + hl];
            ax0 += bf_lo(v) * g.x;
            ay0 += bf_hi(v) * g.y;
        }
        if (p < end && half == 0) {           // odd leftover: half 0 only
            unsigned pk = packed[p];
            unsigned v  = y32[(long)(pk & 0x3FFFF) * 32 + hl];
            float2 g = gate2[(pk >> 18) * 32 + hl];
            ax0 += bf_lo(v) * g.x;
            ay0 += bf_hi(v) * g.y;
        }
        float ax = (ax0 + ax1) + (ax2 + ax3);
        float ay = (ay0 + ay1) + (ay2 + ay3);
        ax += __shfl_xor(ax, 32);
        ay += __shfl_xor(ay, 32);
        float deg = fmaxf((float)(end - beg), 1.0f);
        float2 xv = ((const float2*)x0)[(long)r * 32 + hl];
        float v0 = ax / deg + xv.x;
        float v1 = ay / deg + xv.y;
        v0 = (v0 > 0.0f) ? v0 : (__expf(v0) - 1.0f);
        v1 = (v1 > 0.0f) ? v1 : (__expf(v1) - 1.0f);
        float ss = v0 * v0 + v1 * v1;
        #pragma unroll
        for (int o = 16; o; o >>= 1) ss += __shfl_xor(ss, o);
        float inv = 1.0f / fmaxf(sqrtf(ss), 1e-12f);
        if (half == 0)
            ((float2*)xkg)[(long)r * 32 + hl] = make_float2(v0 * inv, v1 * inv);
    }
}

// ---------------------------------------------------------------------------
// build_all: all_emb = [user_emb ; xkg[i2e]] (f32) + bf16 gather copy all16
// ---------------------------------------------------------------------------
__global__ void build_all(const float* __restrict__ user_emb, const float* __restrict__ xkg,
                          const int* __restrict__ i2e, float* __restrict__ all_emb,
                          unsigned short* __restrict__ all16) {
    int lane = threadIdx.x & 63;
    int wave = (blockIdx.x * blockDim.x + threadIdx.x) >> 6;
    int nw   = (gridDim.x * blockDim.x) >> 6;
    for (int r = wave; r < N_NODES; r += nw) {
        float v;
        if (r < N_USERS) {
            v = user_emb[(long)r * 64 + lane];
        } else {
            long ent = i2e[r - N_USERS];
            v = xkg[ent * 64 + lane];
        }
        all_emb[(long)r * 64 + lane] = v;
        all16[(long)r * 64 + lane]   = f2bf(v);
    }
}

// ---------------------------------------------------------------------------
// ui_aggregate: row-per-wave + half-wave edge pairing (same scheme as kg).
// final = 0.5*(all_emb[r] + dinv[r]*sum(dinv[c]*all16[c]))
// ---------------------------------------------------------------------------
__global__ __launch_bounds__(256) void ui_aggregate(const int* __restrict__ off,
                                                    const int* __restrict__ colrec,
                                                    const float* __restrict__ all_emb,
                                                    const unsigned short* __restrict__ all16,
                                                    const float* __restrict__ dinv,
                                                    float* __restrict__ final_emb) {
    const unsigned* a32 = (const unsigned*)all16;
    int lane = threadIdx.x & 63;
    int hl   = lane & 31;
    int half = lane >> 5;
    int wave = (blockIdx.x * blockDim.x + threadIdx.x) >> 6;
    int nw   = (gridDim.x * blockDim.x) >> 6;
    for (int r = wave; r < N_NODES; r += nw) {
        int beg = off[r], end = off[r + 1];
        float ax0 = 0.f, ay0 = 0.f, ax1 = 0.f, ay1 = 0.f;
        float ax2 = 0.f, ay2 = 0.f, ax3 = 0.f, ay3 = 0.f;
        int p = beg;
        for (; p + 8 <= end; p += 8) {
            int c0 = colrec[p + 0 + half];
            int c1 = colrec[p + 2 + half];
            int c2 = colrec[p + 4 + half];
            int c3 = colrec[p + 6 + half];
            float d0 = dinv[c0], d1 = dinv[c1], d2 = dinv[c2], d3 = dinv[c3];
            unsigned v0 = a32[(long)c0 * 32 + hl];
            unsigned v1 = a32[(long)c1 * 32 + hl];
            unsigned v2 = a32[(long)c2 * 32 + hl];
            unsigned v3 = a32[(long)c3 * 32 + hl];
            ax0 += d0 * bf_lo(v0);  ay0 += d0 * bf_hi(v0);
            ax1 += d1 * bf_lo(v1);  ay1 += d1 * bf_hi(v1);
            ax2 += d2 * bf_lo(v2);  ay2 += d2 * bf_hi(v2);
            ax3 += d3 * bf_lo(v3);  ay3 += d3 * bf_hi(v3);
        }
        for (; p + 2 <= end; p += 2) {
            int c = colrec[p + half];
            float d = dinv[c];
            unsigned v = a32[(long)c * 32 + hl];
            ax0 += d * bf_lo(v);
            ay0 += d * bf_hi(v);
        }
        if (p < end && half == 0) {
            int c = colrec[p];
            float d = dinv[c];
            unsigned v = a32[(long)c * 32 + hl];
            ax0 += d * bf_lo(v);
            ay0 += d * bf_hi(v);
        }
        float ax = (ax0 + ax1) + (ax2 + ax3);
        float ay = (ay0 + ay1) + (ay2 + ay3);
        ax += __shfl_xor(ax, 32);
        ay += __shfl_xor(ay, 32);
        float dr = dinv[r];
        float2 ae = ((const float2*)all_emb)[(long)r * 32 + hl];
        if (half == 0)
            ((float2*)final_emb)[(long)r * 32 + hl] =
                make_float2(0.5f * (ae.x + ax * dr), 0.5f * (ae.y + ay * dr));
    }
}

// ---------------------------------------------------------------------------
// Epilogue (intent folded in): one wave per sample.
// ---------------------------------------------------------------------------
__global__ void final_kernel(const int* __restrict__ u, const int* __restrict__ ipos,
                             const int* __restrict__ ineg,
                             const float* __restrict__ final_emb,
                             const float* __restrict__ all_emb,
                             const float* __restrict__ rw, const float* __restrict__ rb,
                             const float* __restrict__ iw, const float* __restrict__ rel_emb,
                             float* __restrict__ out, int B) {
    __shared__ float sh_intent[128];
    if (threadIdx.x < 64) {
        int j = threadIdx.x;
        for (int k = 0; k < 2; k++) {
            float m = -1e30f;
            for (int r = 0; r < N_REL; r++) m = fmaxf(m, iw[k * N_REL + r]);
            float Z = 0.f, acc = 0.f;
            for (int r = 0; r < N_REL; r++) {
                float e = __expf(iw[k * N_REL + r] - m);
                Z += e;
                acc += e * rel_emb[r * 64 + j];
            }
            sh_intent[k * 64 + j] = acc / Z;
        }
    }
    __syncthreads();
    int lane = threadIdx.x & 63;
    int wave = (blockIdx.x * blockDim.x + threadIdx.x) >> 6;
    int nw   = (gridDim.x * blockDim.x) >> 6;
    for (int b = wave; b < B; b += nw) {
        int uu = u[b];
        float up = final_emb[(long)uu * 64 + lane];
        float l0 = up * rw[lane];
        float l1 = up * rw[64 + lane];
        #pragma unroll
        for (int o = 32; o; o >>= 1) {
            l0 += __shfl_xor(l0, o);
            l1 += __shfl_xor(l1, o);
        }
        l0 += rb[0]; l1 += rb[1];
        float m  = fmaxf(l0, l1);
        float e0 = __expf(l0 - m), e1 = __expf(l1 - m);
        float inv = 1.0f / (e0 + e1);
        float p0 = e0 * inv, p1 = e1 * inv;
        float ue = up + p0 * sh_intent[lane] + p1 * sh_intent[64 + lane];

        int it = ipos[b];
        long rr = (long)(N_USERS + it) * 64 + lane;
        float ie = final_emb[rr] + all_emb[rr];
        float dp = ue * ie;
        #pragma unroll
        for (int o = 32; o; o >>= 1) dp += __shfl_xor(dp, o);
        if (lane == 0) out[b] = dp;

        it = ineg[b];
        rr = (long)(N_USERS + it) * 64 + lane;
        ie = final_emb[rr] + all_emb[rr];
        dp = ue * ie;
        #pragma unroll
        for (int o = 32; o; o >>= 1) dp += __shfl_xor(dp, o);
        if (lane == 0) out[B + b] = dp;
    }
}

extern "C" void kernel_launch(void* const* d_in, const int* in_sizes, int n_in,
                              void* d_out, int out_size, void* d_ws, size_t ws_size,
                              hipStream_t stream) {
    const int*   u          = (const int*)  d_in[0];
    const int*   ipos       = (const int*)  d_in[1];
    const int*   ineg       = (const int*)  d_in[2];
    const float* user_emb   = (const float*)d_in[3];
    const float* entity_emb = (const float*)d_in[4];
    const float* rel_emb    = (const float*)d_in[5];
    const float* iw         = (const float*)d_in[6];
    const float* rw         = (const float*)d_in[7];
    const float* rb         = (const float*)d_in[8];
    const float* kgw        = (const float*)d_in[9];
    const int*   i2e        = (const int*)  d_in[11];
    const int*   kg_src     = (const int*)  d_in[12];
    const int*   kg_dst     = (const int*)  d_in[13];
    const int*   kg_rel     = (const int*)  d_in[14];
    const int*   ui_row     = (const int*)  d_in[15];
    const int*   ui_col     = (const int*)  d_in[16];
    float*       out        = (float*)d_out;

    int B    = in_sizes[0];
    int e_kg = in_sizes[12];
    int e_ui = in_sizes[15];

    // ---------------- workspace layout (bytes) ----------------
    char* ws = (char*)d_ws;
    unsigned short* y16       = (unsigned short*)(ws + 0);   // 25.6 MB
    float*          all_emb   = (float*)(ws + 0);            // 38.4 MB (after kg_agg)
    float*          xkg       = (float*)(ws + 38400000);     // 51.2 MB
    float*          final_emb = (float*)(ws + 38400000);     // 38.4 MB (after build_all)
    unsigned short* all16     = (unsigned short*)(ws + 89600000); // 19.2 MB
    unsigned int*   kgrec     = (unsigned int*)(ws + 108800000);  // 8 MB
    int*            uirec     = (int*)(ws + 116800000);      // 8 MB
    int*            off_kg    = (int*)(ws + 124800000);      // 200001 ints
    int*            off_ui    = (int*)(ws + 125600256);      // 150001 ints
    float*          dinv      = (float*)(ws + 126200512);    // 150000 floats
    int*            bcnt      = (int*)(ws + 126800512);      // 977 ints
    int*            boff_kg   = (int*)(ws + 126804480);      // 392 ints
    int*            boff_ui   = (int*)(ws + 126806272);      // 587 ints
    int*            bcur      = (int*)(ws + 126808704);      // 977 ints

    hipMemsetAsync(bcnt, 0, NB_TOT * sizeof(int), stream);
    bucket_hist    <<<256, 256, 0, stream>>>(kg_dst, ui_row, bcnt, e_kg, e_ui);
    bucket_scan    <<<1,   256, 0, stream>>>(bcnt, boff_kg, boff_ui, bcur, e_kg, e_ui);
    bucket_scatter <<<512, 256, 0, stream>>>(kg_src, kg_dst, kg_rel, ui_row, ui_col,
                                             bcur, kgrec, uirec, e_kg, e_ui);
    bucket_finalize<<<NB_TOT, 256, 0, stream>>>(boff_kg, boff_ui, kgrec, uirec,
                                                off_kg, off_ui, dinv, e_kg, e_ui);

    ent_matmul  <<<(N_ENT + 127) / 128, 128, 0, stream>>>(entity_emb, kgw, y16, N_ENT);
    kg_aggregate<<<4096, 256, 0, stream>>>(off_kg, kgrec, y16, entity_emb, rel_emb,
                                           xkg, N_ENT);
    build_all   <<<2048, 256, 0, stream>>>(user_emb, xkg, i2e, all_emb, all16);
    ui_aggregate<<<4096, 256, 0, stream>>>(off_ui, uirec, all_emb, all16, dinv, final_emb);
    final_kernel<<<256,  256, 0, stream>>>(u, ipos, ineg, final_emb, all_emb,
                                           rw, rb, iw, rel_emb, out, B);
}

// Round 11
// 417.357 us; speedup vs baseline: 1.8221x; 1.1678x over previous
//
#include <hip/hip_runtime.h>
#include <math.h>

#define N_USERS 50000
#define N_ITEMS 100000
#define N_ENT   200000
#define N_NODES (N_USERS + N_ITEMS)
#define N_REL   32
#define DIM     64

#define NB_KG  391          // KG buckets: dst>>9 (512 keys each)
#define NB_UI  586          // UI buckets: row>>8 (256 keys each)
#define NB_TOT (NB_KG + NB_UI)   // 977
#define CAPD   8192         // max edges per bucket in finalize LDS

__device__ __forceinline__ unsigned short f2bf(float f) {   // RNE f32->bf16
    unsigned u = __float_as_uint(f);
    u += 0x7FFFu + ((u >> 16) & 1u);
    return (unsigned short)(u >> 16);
}
__device__ __forceinline__ float bf_lo(unsigned v) { return __uint_as_float(v << 16); }
__device__ __forceinline__ float bf_hi(unsigned v) { return __uint_as_float(v & 0xFFFF0000u); }

// ---------------------------------------------------------------------------
// ent_matmul: y16 = bf16(x @ W^T), register-tiled LDS GEMM (R7 form).
// ---------------------------------------------------------------------------
__global__ __launch_bounds__(128) void ent_matmul(const float* __restrict__ x,
                                                  const float* __restrict__ w,
                                                  unsigned short* __restrict__ y16,
                                                  int n_ent) {
    __shared__ float xt[64][132];
    __shared__ float wt[64][68];
    int tid  = threadIdx.x;
    int base = blockIdx.x * 128;

    #pragma unroll
    for (int q = 0; q < 8; q++) {
        int idx = q * 128 + tid;
        int j = idx >> 4, k4 = idx & 15;
        float4 v = ((const float4*)w)[idx];
        wt[4 * k4 + 0][j] = v.x;
        wt[4 * k4 + 1][j] = v.y;
        wt[4 * k4 + 2][j] = v.z;
        wt[4 * k4 + 3][j] = v.w;
    }
    #pragma unroll
    for (int q = 0; q < 16; q++) {
        int idx = q * 128 + tid;
        int r = idx >> 4, k4 = idx & 15;
        int gr = base + r;
        if (gr < n_ent) {
            float4 v = ((const float4*)x)[(long)gr * 16 + k4];
            xt[4 * k4 + 0][r] = v.x;
            xt[4 * k4 + 1][r] = v.y;
            xt[4 * k4 + 2][r] = v.z;
            xt[4 * k4 + 3][r] = v.w;
        }
    }
    __syncthreads();

    int j0 = (tid & 7) * 8;
    int r0 = (tid >> 3) * 8;
    float acc[8][8];
    #pragma unroll
    for (int i = 0; i < 8; i++)
        #pragma unroll
        for (int j = 0; j < 8; j++) acc[i][j] = 0.f;

    #pragma unroll 4
    for (int k = 0; k < 64; k++) {
        float4 xa = *(const float4*)&xt[k][r0];
        float4 xb = *(const float4*)&xt[k][r0 + 4];
        float4 wa = *(const float4*)&wt[k][j0];
        float4 wb = *(const float4*)&wt[k][j0 + 4];
        float xr[8] = {xa.x, xa.y, xa.z, xa.w, xb.x, xb.y, xb.z, xb.w};
        float wr[8] = {wa.x, wa.y, wa.z, wa.w, wb.x, wb.y, wb.z, wb.w};
        #pragma unroll
        for (int i = 0; i < 8; i++)
            #pragma unroll
            for (int j = 0; j < 8; j++)
                acc[i][j] += xr[i] * wr[j];
    }

    #pragma unroll
    for (int i = 0; i < 8; i++) {
        int gr = base + r0 + i;
        if (gr < n_ent) {
            uint4 o;
            o.x = (unsigned)f2bf(acc[i][0]) | ((unsigned)f2bf(acc[i][1]) << 16);
            o.y = (unsigned)f2bf(acc[i][2]) | ((unsigned)f2bf(acc[i][3]) << 16);
            o.z = (unsigned)f2bf(acc[i][4]) | ((unsigned)f2bf(acc[i][5]) << 16);
            o.w = (unsigned)f2bf(acc[i][6]) | ((unsigned)f2bf(acc[i][7]) << 16);
            *(uint4*)&y16[(long)gr * 64 + j0] = o;
        }
    }
}

// ---------------------------------------------------------------------------
// Pass A: per-block LDS bucket histogram
// ---------------------------------------------------------------------------
__global__ __launch_bounds__(256) void bucket_hist(const int* __restrict__ kg_dst,
                                                   const int* __restrict__ ui_row,
                                                   int* __restrict__ bcnt,
                                                   int e_kg, int e_ui) {
    __shared__ int h[NB_TOT];
    for (int i = threadIdx.x; i < NB_TOT; i += 256) h[i] = 0;
    __syncthreads();
    int n = e_kg + e_ui;
    int t = blockIdx.x * 256 + threadIdx.x;
    int stride = gridDim.x * 256;
    for (int e = t; e < n; e += stride) {
        int bk = (e < e_kg) ? (kg_dst[e] >> 9) : (NB_KG + (ui_row[e - e_kg] >> 8));
        atomicAdd(&h[bk], 1);
    }
    __syncthreads();
    for (int i = threadIdx.x; i < NB_TOT; i += 256)
        if (h[i]) atomicAdd(&bcnt[i], h[i]);
}

// ---------------------------------------------------------------------------
// Pass B: exclusive scan of bucket counts
// ---------------------------------------------------------------------------
__global__ __launch_bounds__(256) void bucket_scan(const int* __restrict__ bcnt,
                                                   int* __restrict__ boff_kg,
                                                   int* __restrict__ boff_ui,
                                                   int* __restrict__ bcur,
                                                   int e_kg, int e_ui) {
    __shared__ int sh[1024];
    int t = threadIdx.x;
    for (int seg = 0; seg < 2; seg++) {
        int NB = seg ? NB_UI : NB_KG;
        const int* src = bcnt + (seg ? NB_KG : 0);
        int idx[4] = { t, t + 256, t + 512, t + 768 };
        int v[4];
        #pragma unroll
        for (int q = 0; q < 4; q++) {
            v[q] = (idx[q] < NB) ? src[idx[q]] : 0;
            sh[idx[q]] = v[q];
        }
        __syncthreads();
        for (int o = 1; o < 1024; o <<= 1) {
            int a[4];
            #pragma unroll
            for (int q = 0; q < 4; q++) a[q] = (idx[q] >= o) ? sh[idx[q] - o] : 0;
            __syncthreads();
            #pragma unroll
            for (int q = 0; q < 4; q++) sh[idx[q]] += a[q];
            __syncthreads();
        }
        int* boff = seg ? boff_ui : boff_kg;
        int  base = seg ? NB_KG : 0;
        #pragma unroll
        for (int q = 0; q < 4; q++) {
            if (idx[q] < NB) {
                int ex = sh[idx[q]] - v[q];
                boff[idx[q]] = ex;
                bcur[base + idx[q]] = ex;
            }
        }
        if (t == 0) boff[NB] = seg ? e_ui : e_kg;
        __syncthreads();
    }
}

// ---------------------------------------------------------------------------
// Pass C: scatter edges into bucket regions.
// KG rec: src(18) | rel<<18 (5) | dst_local<<23 (9)
// UI rec: col(18) | row_local<<18 (8)
// ---------------------------------------------------------------------------
__global__ __launch_bounds__(256) void bucket_scatter(const int* __restrict__ kg_src,
                                                      const int* __restrict__ kg_dst,
                                                      const int* __restrict__ kg_rel,
                                                      const int* __restrict__ ui_row,
                                                      const int* __restrict__ ui_col,
                                                      int* __restrict__ bcur,
                                                      unsigned int* __restrict__ kgrec,
                                                      int* __restrict__ uirec,
                                                      int e_kg, int e_ui) {
    __shared__ int h[NB_TOT];
    __shared__ int lbase[NB_TOT];
    int n = e_kg + e_ui;
    int nchunks = (n + 4095) >> 12;
    int tid = threadIdx.x;
    for (int c = blockIdx.x; c < nchunks; c += gridDim.x) {
        int base = c << 12;
        for (int i = tid; i < NB_TOT; i += 256) h[i] = 0;
        __syncthreads();
        unsigned int rec[16];
        int bk[16];
        #pragma unroll
        for (int j = 0; j < 16; j++) {
            int e = base + j * 256 + tid;
            if (e < n) {
                if (e < e_kg) {
                    int d = kg_dst[e];
                    bk[j]  = d >> 9;
                    rec[j] = (unsigned int)kg_src[e] | ((unsigned int)kg_rel[e] << 18)
                             | ((unsigned int)(d & 511) << 23);
                } else {
                    int i2 = e - e_kg;
                    int r  = ui_row[i2];
                    bk[j]  = NB_KG + (r >> 8);
                    rec[j] = (unsigned int)ui_col[i2] | ((unsigned int)(r & 255) << 18);
                }
                atomicAdd(&h[bk[j]], 1);
            } else bk[j] = -1;
        }
        __syncthreads();
        for (int i = tid; i < NB_TOT; i += 256) {
            int cc = h[i];
            lbase[i] = cc ? atomicAdd(&bcur[i], cc) : 0;
        }
        __syncthreads();
        #pragma unroll
        for (int j = 0; j < 16; j++) {
            if (bk[j] >= 0) {
                int pos = atomicAdd(&lbase[bk[j]], 1);
                if (bk[j] < NB_KG) kgrec[pos] = rec[j];
                else               uirec[pos] = (int)rec[j];
            }
        }
        __syncthreads();
    }
}

// ---------------------------------------------------------------------------
// Pass D: one block per bucket. LDS counting-sort; emits CSR off[], sorted
// records, and (UI) dinv[].
// ---------------------------------------------------------------------------
__global__ __launch_bounds__(256) void bucket_finalize(const int* __restrict__ boff_kg,
                                                       const int* __restrict__ boff_ui,
                                                       unsigned int* __restrict__ kgrec,
                                                       int* __restrict__ uirec,
                                                       int* __restrict__ off_kg,
                                                       int* __restrict__ off_ui,
                                                       float* __restrict__ dinv,
                                                       int e_kg, int e_ui) {
    __shared__ unsigned int rec[CAPD];
    __shared__ int hist[512];
    bool iskg = blockIdx.x < NB_KG;
    int  b    = iskg ? blockIdx.x : blockIdx.x - NB_KG;
    const int* boff = iskg ? boff_kg : boff_ui;
    int ebeg = boff[b], eend = boff[b + 1];
    int ne   = min(eend - ebeg, CAPD);
    int key_base = iskg ? (b << 9) : (b << 8);
    int nkeys = iskg ? min(512, N_ENT - key_base) : min(256, N_NODES - key_base);
    int SH = iskg ? 23 : 18;
    int tid = threadIdx.x;

    for (int i = tid; i < ne; i += 256)
        rec[i] = iskg ? kgrec[ebeg + i] : (unsigned int)uirec[ebeg + i];
    for (int i = tid; i < 512; i += 256) hist[i] = 0;
    __syncthreads();
    for (int i = tid; i < ne; i += 256)
        atomicAdd(&hist[rec[i] >> SH], 1);
    __syncthreads();
    if (!iskg) {
        for (int i = tid; i < nkeys; i += 256) {
            int d = hist[i];
            dinv[key_base + i] = d > 0 ? 1.0f / sqrtf((float)d) : 0.0f;
        }
    }
    int i0 = tid, i1 = tid + 256;
    int v0 = hist[i0], v1 = hist[i1];
    __syncthreads();
    for (int o = 1; o < 512; o <<= 1) {
        int a0 = (i0 >= o) ? hist[i0 - o] : 0;
        int a1 = (i1 >= o) ? hist[i1 - o] : 0;
        __syncthreads();
        hist[i0] += a0; hist[i1] += a1;
        __syncthreads();
    }
    int e0 = hist[i0] - v0, e1 = hist[i1] - v1;
    __syncthreads();
    hist[i0] = e0; hist[i1] = e1;
    int* offg = iskg ? off_kg : off_ui;
    if (i0 < nkeys) offg[key_base + i0] = ebeg + e0;
    if (i1 < nkeys) offg[key_base + i1] = ebeg + e1;
    if (blockIdx.x == 0 && tid == 0) {
        off_kg[N_ENT]   = e_kg;
        off_ui[N_NODES] = e_ui;
    }
    __syncthreads();
    for (int i = tid; i < ne; i += 256) {
        unsigned int r = rec[i];
        int k = r >> SH;
        int slot = atomicAdd(&hist[k], 1);
        if (iskg) kgrec[ebeg + slot] = r & 0x7FFFFFu;
        else      uirec[ebeg + slot] = (int)(r & 0x3FFFFu);
    }
}

// ---------------------------------------------------------------------------
// kgagg_build: ONE WAVE PER NODE. Users: copy user_emb. Items: run the KG
// aggregate (half-wave edge pairing, R10 loop) on ent=i2e[it] and write the
// f32 + bf16 all-embedding rows directly (xkg buffer & build_all eliminated;
// only the ~100K entities actually referenced are computed — duplicates
// recompute identical values, each OUTPUT row written exactly once).
// ---------------------------------------------------------------------------
__global__ __launch_bounds__(256) void kgagg_build(const int* __restrict__ off,
                                                   const unsigned int* __restrict__ packed,
                                                   const unsigned short* __restrict__ y16,
                                                   const float* __restrict__ entity_emb,
                                                   const float* __restrict__ user_emb,
                                                   const int* __restrict__ i2e,
                                                   const float* __restrict__ rel_emb,
                                                   float* __restrict__ all_emb,
                                                   unsigned short* __restrict__ all16) {
    __shared__ float2 gate2[N_REL * 32];
    for (int idx = threadIdx.x; idx < N_REL * 32; idx += 256) {
        int rel = idx >> 5, hl2 = idx & 31;
        float g0 = 1.0f / (1.0f + __expf(-rel_emb[rel * 64 + 2 * hl2]));
        float g1 = 1.0f / (1.0f + __expf(-rel_emb[rel * 64 + 2 * hl2 + 1]));
        gate2[idx] = make_float2(g0, g1);
    }
    __syncthreads();
    int lane = threadIdx.x & 63;
    int w = (blockIdx.x * 256 + threadIdx.x) >> 6;
    if (w >= N_NODES) return;

    if (w < N_USERS) {                    // user row: plain copy
        float v = user_emb[(long)w * 64 + lane];
        all_emb[(long)w * 64 + lane] = v;
        all16[(long)w * 64 + lane]   = f2bf(v);
        return;
    }

    int ent = i2e[w - N_USERS];
    const unsigned* y32 = (const unsigned*)y16;
    int hl   = lane & 31;
    int half = lane >> 5;
    int beg = off[ent], end = off[ent + 1];
    float ax0 = 0.f, ay0 = 0.f, ax1 = 0.f, ay1 = 0.f;
    float ax2 = 0.f, ay2 = 0.f, ax3 = 0.f, ay3 = 0.f;
    int p = beg;
    for (; p + 8 <= end; p += 8) {
        unsigned pk0 = packed[p + 0 + half];
        unsigned pk1 = packed[p + 2 + half];
        unsigned pk2 = packed[p + 4 + half];
        unsigned pk3 = packed[p + 6 + half];
        unsigned v0 = y32[(long)(pk0 & 0x3FFFF) * 32 + hl];
        unsigned v1 = y32[(long)(pk1 & 0x3FFFF) * 32 + hl];
        unsigned v2 = y32[(long)(pk2 & 0x3FFFF) * 32 + hl];
        unsigned v3 = y32[(long)(pk3 & 0x3FFFF) * 32 + hl];
        float2 g0 = gate2[(pk0 >> 18) * 32 + hl];
        float2 g1 = gate2[(pk1 >> 18) * 32 + hl];
        float2 g2 = gate2[(pk2 >> 18) * 32 + hl];
        float2 g3 = gate2[(pk3 >> 18) * 32 + hl];
        ax0 += bf_lo(v0) * g0.x;  ay0 += bf_hi(v0) * g0.y;
        ax1 += bf_lo(v1) * g1.x;  ay1 += bf_hi(v1) * g1.y;
        ax2 += bf_lo(v2) * g2.x;  ay2 += bf_hi(v2) * g2.y;
        ax3 += bf_lo(v3) * g3.x;  ay3 += bf_hi(v3) * g3.y;
    }
    for (; p + 2 <= end; p += 2) {
        unsigned pk = packed[p + half];
        unsigned v  = y32[(long)(pk & 0x3FFFF) * 32 + hl];
        float2 g = gate2[(pk >> 18) * 32 + hl];
        ax0 += bf_lo(v) * g.x;
        ay0 += bf_hi(v) * g.y;
    }
    if (p < end && half == 0) {
        unsigned pk = packed[p];
        unsigned v  = y32[(long)(pk & 0x3FFFF) * 32 + hl];
        float2 g = gate2[(pk >> 18) * 32 + hl];
        ax0 += bf_lo(v) * g.x;
        ay0 += bf_hi(v) * g.y;
    }
    float ax = (ax0 + ax1) + (ax2 + ax3);
    float ay = (ay0 + ay1) + (ay2 + ay3);
    ax += __shfl_xor(ax, 32);
    ay += __shfl_xor(ay, 32);
    float deg = fmaxf((float)(end - beg), 1.0f);
    float2 xv = ((const float2*)entity_emb)[(long)ent * 32 + hl];
    float v0 = ax / deg + xv.x;
    float v1 = ay / deg + xv.y;
    v0 = (v0 > 0.0f) ? v0 : (__expf(v0) - 1.0f);
    v1 = (v1 > 0.0f) ? v1 : (__expf(v1) - 1.0f);
    float ss = v0 * v0 + v1 * v1;
    #pragma unroll
    for (int o = 16; o; o >>= 1) ss += __shfl_xor(ss, o);
    float inv = 1.0f / fmaxf(sqrtf(ss), 1e-12f);
    if (half == 0) {
        float a = v0 * inv, b = v1 * inv;
        ((float2*)all_emb)[(long)w * 32 + hl] = make_float2(a, b);
        ((unsigned*)all16)[(long)w * 32 + hl] =
            (unsigned)f2bf(a) | ((unsigned)f2bf(b) << 16);
    }
}

// ---------------------------------------------------------------------------
// ui_aggregate_s: one wave per SAMPLE ROW (3B waves). Only rows the output
// reads are computed (~12K of 150K). Duplicate rows write identical values.
// ---------------------------------------------------------------------------
__global__ __launch_bounds__(256) void ui_aggregate_s(const int* __restrict__ off,
                                                      const int* __restrict__ colrec,
                                                      const float* __restrict__ all_emb,
                                                      const unsigned short* __restrict__ all16,
                                                      const float* __restrict__ dinv,
                                                      const int* __restrict__ u,
                                                      const int* __restrict__ ipos,
                                                      const int* __restrict__ ineg,
                                                      float* __restrict__ final_emb, int B) {
    const unsigned* a32 = (const unsigned*)all16;
    int lane = threadIdx.x & 63;
    int hl   = lane & 31;
    int half = lane >> 5;
    int w = (blockIdx.x * 256 + threadIdx.x) >> 6;
    if (w >= 3 * B) return;
    int r;
    if (w < B)          r = u[w];
    else if (w < 2 * B) r = N_USERS + ipos[w - B];
    else                r = N_USERS + ineg[w - 2 * B];

    int beg = off[r], end = off[r + 1];
    float ax0 = 0.f, ay0 = 0.f, ax1 = 0.f, ay1 = 0.f;
    float ax2 = 0.f, ay2 = 0.f, ax3 = 0.f, ay3 = 0.f;
    int p = beg;
    for (; p + 8 <= end; p += 8) {
        int c0 = colrec[p + 0 + half];
        int c1 = colrec[p + 2 + half];
        int c2 = colrec[p + 4 + half];
        int c3 = colrec[p + 6 + half];
        float d0 = dinv[c0], d1 = dinv[c1], d2 = dinv[c2], d3 = dinv[c3];
        unsigned v0 = a32[(long)c0 * 32 + hl];
        unsigned v1 = a32[(long)c1 * 32 + hl];
        unsigned v2 = a32[(long)c2 * 32 + hl];
        unsigned v3 = a32[(long)c3 * 32 + hl];
        ax0 += d0 * bf_lo(v0);  ay0 += d0 * bf_hi(v0);
        ax1 += d1 * bf_lo(v1);  ay1 += d1 * bf_hi(v1);
        ax2 += d2 * bf_lo(v2);  ay2 += d2 * bf_hi(v2);
        ax3 += d3 * bf_lo(v3);  ay3 += d3 * bf_hi(v3);
    }
    for (; p + 2 <= end; p += 2) {
        int c = colrec[p + half];
        float d = dinv[c];
        unsigned v = a32[(long)c * 32 + hl];
        ax0 += d * bf_lo(v);
        ay0 += d * bf_hi(v);
    }
    if (p < end && half == 0) {
        int c = colrec[p];
        float d = dinv[c];
        unsigned v = a32[(long)c * 32 + hl];
        ax0 += d * bf_lo(v);
        ay0 += d * bf_hi(v);
    }
    float ax = (ax0 + ax1) + (ax2 + ax3);
    float ay = (ay0 + ay1) + (ay2 + ay3);
    ax += __shfl_xor(ax, 32);
    ay += __shfl_xor(ay, 32);
    float dr = dinv[r];
    float2 ae = ((const float2*)all_emb)[(long)r * 32 + hl];
    if (half == 0)
        ((float2*)final_emb)[(long)r * 32 + hl] =
            make_float2(0.5f * (ae.x + ax * dr), 0.5f * (ae.y + ay * dr));
}

// ---------------------------------------------------------------------------
// Epilogue (intent folded in): one wave per sample.
// ---------------------------------------------------------------------------
__global__ void final_kernel(const int* __restrict__ u, const int* __restrict__ ipos,
                             const int* __restrict__ ineg,
                             const float* __restrict__ final_emb,
                             const float* __restrict__ all_emb,
                             const float* __restrict__ rw, const float* __restrict__ rb,
                             const float* __restrict__ iw, const float* __restrict__ rel_emb,
                             float* __restrict__ out, int B) {
    __shared__ float sh_intent[128];
    if (threadIdx.x < 64) {
        int j = threadIdx.x;
        for (int k = 0; k < 2; k++) {
            float m = -1e30f;
            for (int r = 0; r < N_REL; r++) m = fmaxf(m, iw[k * N_REL + r]);
            float Z = 0.f, acc = 0.f;
            for (int r = 0; r < N_REL; r++) {
                float e = __expf(iw[k * N_REL + r] - m);
                Z += e;
                acc += e * rel_emb[r * 64 + j];
            }
            sh_intent[k * 64 + j] = acc / Z;
        }
    }
    __syncthreads();
    int lane = threadIdx.x & 63;
    int wave = (blockIdx.x * blockDim.x + threadIdx.x) >> 6;
    int nw   = (gridDim.x * blockDim.x) >> 6;
    for (int b = wave; b < B; b += nw) {
        int uu = u[b];
        float up = final_emb[(long)uu * 64 + lane];
        float l0 = up * rw[lane];
        float l1 = up * rw[64 + lane];
        #pragma unroll
        for (int o = 32; o; o >>= 1) {
            l0 += __shfl_xor(l0, o);
            l1 += __shfl_xor(l1, o);
        }
        l0 += rb[0]; l1 += rb[1];
        float m  = fmaxf(l0, l1);
        float e0 = __expf(l0 - m), e1 = __expf(l1 - m);
        float inv = 1.0f / (e0 + e1);
        float p0 = e0 * inv, p1 = e1 * inv;
        float ue = up + p0 * sh_intent[lane] + p1 * sh_intent[64 + lane];

        int it = ipos[b];
        long rr = (long)(N_USERS + it) * 64 + lane;
        float ie = final_emb[rr] + all_emb[rr];
        float dp = ue * ie;
        #pragma unroll
        for (int o = 32; o; o >>= 1) dp += __shfl_xor(dp, o);
        if (lane == 0) out[b] = dp;

        it = ineg[b];
        rr = (long)(N_USERS + it) * 64 + lane;
        ie = final_emb[rr] + all_emb[rr];
        dp = ue * ie;
        #pragma unroll
        for (int o = 32; o; o >>= 1) dp += __shfl_xor(dp, o);
        if (lane == 0) out[B + b] = dp;
    }
}

extern "C" void kernel_launch(void* const* d_in, const int* in_sizes, int n_in,
                              void* d_out, int out_size, void* d_ws, size_t ws_size,
                              hipStream_t stream) {
    const int*   u          = (const int*)  d_in[0];
    const int*   ipos       = (const int*)  d_in[1];
    const int*   ineg       = (const int*)  d_in[2];
    const float* user_emb   = (const float*)d_in[3];
    const float* entity_emb = (const float*)d_in[4];
    const float* rel_emb    = (const float*)d_in[5];
    const float* iw         = (const float*)d_in[6];
    const float* rw         = (const float*)d_in[7];
    const float* rb         = (const float*)d_in[8];
    const float* kgw        = (const float*)d_in[9];
    const int*   i2e        = (const int*)  d_in[11];
    const int*   kg_src     = (const int*)  d_in[12];
    const int*   kg_dst     = (const int*)  d_in[13];
    const int*   kg_rel     = (const int*)  d_in[14];
    const int*   ui_row     = (const int*)  d_in[15];
    const int*   ui_col     = (const int*)  d_in[16];
    float*       out        = (float*)d_out;

    int B    = in_sizes[0];
    int e_kg = in_sizes[12];
    int e_ui = in_sizes[15];

    // ---------------- workspace layout (bytes) ----------------
    // No xkg buffer anymore; y16 stays live through kgagg_build, so all_emb
    // gets its own region.
    char* ws = (char*)d_ws;
    unsigned short* y16       = (unsigned short*)(ws + 0);        // 25.6 MB
    float*          all_emb   = (float*)(ws + 25600000);          // 38.4 MB
    unsigned short* all16     = (unsigned short*)(ws + 64000000); // 19.2 MB
    float*          final_emb = (float*)(ws + 83200000);          // 38.4 MB (sparse use)
    unsigned int*   kgrec     = (unsigned int*)(ws + 121600000);  // 8 MB
    int*            uirec     = (int*)(ws + 129600000);           // 8 MB
    int*            off_kg    = (int*)(ws + 137600000);           // 200001 ints
    int*            off_ui    = (int*)(ws + 138400256);           // 150001 ints
    float*          dinv      = (float*)(ws + 139000512);         // 150000 floats
    int*            bcnt      = (int*)(ws + 139600512);           // 977 ints
    int*            boff_kg   = (int*)(ws + 139604480);           // 392 ints
    int*            boff_ui   = (int*)(ws + 139606272);           // 587 ints
    int*            bcur      = (int*)(ws + 139608704);           // 977 ints

    hipMemsetAsync(bcnt, 0, NB_TOT * sizeof(int), stream);
    bucket_hist    <<<256, 256, 0, stream>>>(kg_dst, ui_row, bcnt, e_kg, e_ui);
    bucket_scan    <<<1,   256, 0, stream>>>(bcnt, boff_kg, boff_ui, bcur, e_kg, e_ui);
    bucket_scatter <<<512, 256, 0, stream>>>(kg_src, kg_dst, kg_rel, ui_row, ui_col,
                                             bcur, kgrec, uirec, e_kg, e_ui);
    bucket_finalize<<<NB_TOT, 256, 0, stream>>>(boff_kg, boff_ui, kgrec, uirec,
                                                off_kg, off_ui, dinv, e_kg, e_ui);

    ent_matmul <<<(N_ENT + 127) / 128, 128, 0, stream>>>(entity_emb, kgw, y16, N_ENT);
    kgagg_build<<<(N_NODES * 64 + 255) / 256, 256, 0, stream>>>(
        off_kg, kgrec, y16, entity_emb, user_emb, i2e, rel_emb, all_emb, all16);
    ui_aggregate_s<<<(3 * B * 64 + 255) / 256, 256, 0, stream>>>(
        off_ui, uirec, all_emb, all16, dinv, u, ipos, ineg, final_emb, B);
    final_kernel<<<256, 256, 0, stream>>>(u, ipos, ineg, final_emb, all_emb,
                                          rw, rb, iw, rel_emb, out, B);
}